// Round 1
// baseline (136.073 us; speedup 1.0000x reference)
//
#include <hip/hip_runtime.h>
#include <hip/hip_bf16.h>

#define NR 4096

typedef float f32x4 __attribute__((ext_vector_type(4)));
typedef __bf16 bf16x8 __attribute__((ext_vector_type(8)));

typedef __attribute__((address_space(1))) unsigned int u32_g;
typedef __attribute__((address_space(3))) unsigned int u32_l;

__device__ __forceinline__ void gl_lds16(const void* g, void* l) {
  // global -> LDS direct copy, 16B per lane; LDS dest = wave-uniform base + lane*16
  __builtin_amdgcn_global_load_lds((const u32_g*)g, (u32_l*)l, 16, 0, 0);
}

// ---------------- weight transpose + fp32->bf16 convert ----------------
// in:  fp32 [E][Kin][Oin]   out: bf16 [E][OP][KP]  (zero padded)
__global__ void transpose_cvt(const float* __restrict__ in, __hip_bfloat16* __restrict__ out,
                              int Kin, int Oin, int KP, int OP)
{
  __shared__ float t[32][33];
  int e = blockIdx.z;
  int k0 = blockIdx.x * 32, o0 = blockIdx.y * 32;
  int tx = threadIdx.x & 31, ty = threadIdx.x >> 5;  // 32 x 8
#pragma unroll
  for (int i = 0; i < 4; ++i) {
    int k = k0 + ty + i * 8;
    int o = o0 + tx;
    float v = (k < Kin && o < Oin) ? in[((size_t)e * Kin + k) * Oin + o] : 0.f;
    t[ty + i * 8][tx] = v;
  }
  __syncthreads();
#pragma unroll
  for (int i = 0; i < 4; ++i) {
    int o = o0 + ty + i * 8;
    int k = k0 + tx;
    if (o < OP && k < KP)
      out[((size_t)e * OP + o) * KP + k] = __float2bfloat16(t[tx][ty + i * 8]);
  }
}

// ---------------- build padded bf16 inputs ----------------
// x0 [N][288] = [condition(219) | latent(64) | 0(5)]
// x1 [N][576]: fill cols 512..575 with latent (cols 0..511 written by blend0)
__global__ void build_x(const float* __restrict__ cond, const float* __restrict__ lat,
                        __hip_bfloat16* __restrict__ x0, __hip_bfloat16* __restrict__ x1)
{
  int idx = blockIdx.x * 256 + threadIdx.x;
  const int T0 = NR * 288;
  if (idx < T0) {
    int n = idx / 288, k = idx - (idx / 288) * 288;
    float v = 0.f;
    if (k < 219) v = cond[(size_t)n * 219 + k];
    else if (k < 283) v = lat[(size_t)n * 64 + (k - 219)];
    x0[idx] = __float2bfloat16(v);
  } else {
    int i2 = idx - T0;
    if (i2 < NR * 64) {
      int n = i2 >> 6, j = i2 & 63;
      x1[(size_t)n * 576 + 512 + j] = __float2bfloat16(lat[i2]);
    }
  }
}

// ---------------- gate network (exact fp32) ----------------
// 16 rows per 128-thread block; thread t owns output column t.
__global__ __launch_bounds__(128) void gate_kernel(
    const float* __restrict__ phase, const float* __restrict__ latent,
    const float* __restrict__ w1, const float* __restrict__ b1,
    const float* __restrict__ w2, const float* __restrict__ b2,
    const float* __restrict__ w3, const float* __restrict__ b3,
    float* __restrict__ coeff_out)
{
  __shared__ float g0[16][104];
  __shared__ float h1[16][128];
  __shared__ float h2[16][129];  // +1 pad: layer-3 reads 16 rows in parallel
  __shared__ float lg[16][8];
  int n0 = blockIdx.x * 16;
  int t = threadIdx.x;

  for (int i = t; i < 16 * 104; i += 128) {
    int r = i / 104, c = i - r * 104;
    float v = (c < 40) ? phase[(size_t)(n0 + r) * 40 + c]
                       : latent[(size_t)(n0 + r) * 64 + (c - 40)];
    g0[r][c] = v;
  }
  __syncthreads();
  {
    float acc[16];
#pragma unroll
    for (int r = 0; r < 16; ++r) acc[r] = 0.f;
    for (int k = 0; k < 104; ++k) {
      float w = w1[k * 128 + t];
#pragma unroll
      for (int r = 0; r < 16; ++r) acc[r] += g0[r][k] * w;
    }
    float bb = b1[t];
#pragma unroll
    for (int r = 0; r < 16; ++r) { float v = acc[r] + bb; h1[r][t] = v > 0.f ? v : expm1f(v); }
  }
  __syncthreads();
  {
    float acc[16];
#pragma unroll
    for (int r = 0; r < 16; ++r) acc[r] = 0.f;
    for (int k = 0; k < 128; ++k) {
      float w = w2[k * 128 + t];
#pragma unroll
      for (int r = 0; r < 16; ++r) acc[r] += h1[r][k] * w;
    }
    float bb = b2[t];
#pragma unroll
    for (int r = 0; r < 16; ++r) { float v = acc[r] + bb; h2[r][t] = v > 0.f ? v : expm1f(v); }
  }
  __syncthreads();
  {
    int r = t >> 3, e = t & 7;
    float acc = 0.f;
    for (int k = 0; k < 128; ++k) acc += h2[r][k] * w3[k * 8 + e];
    lg[r][e] = acc + b3[e];
  }
  __syncthreads();
  if (t < 16) {
    float mx = lg[t][0];
#pragma unroll
    for (int e = 1; e < 8; ++e) mx = fmaxf(mx, lg[t][e]);
    float ex[8]; float s = 0.f;
#pragma unroll
    for (int e = 0; e < 8; ++e) { ex[e] = expf(lg[t][e] - mx); s += ex[e]; }
    float inv = 1.f / s;
#pragma unroll
    for (int e = 0; e < 8; ++e) coeff_out[(size_t)(n0 + t) * 8 + e] = ex[e] * inv;
  }
}

// ---------------- bf16 MFMA GEMM (m97 structure) ----------------
// X [NR][KP] bf16 row-major, W [J][KP] bf16 (pre-transposed), H [NR][J] bf16.
// 128x128 tile, BK=32, 4 waves in 2x2, wave tile 64x64, 16x16x32 MFMA.
template <int KP>
__global__ __launch_bounds__(256) void gemm_bf16(const __hip_bfloat16* __restrict__ X,
                                                 const __hip_bfloat16* __restrict__ W,
                                                 __hip_bfloat16* __restrict__ H, int J)
{
  __shared__ __align__(16) __hip_bfloat16 Xs[128][32];
  __shared__ __align__(16) __hip_bfloat16 Ws[128][32];
  const int tid = threadIdx.x;
  const int lane = tid & 63;
  const int wid = tid >> 6;
  const int wr = wid >> 1, wc = wid & 1;
  const int m0 = blockIdx.x * 128;
  const int j0 = blockIdx.y * 128;

  f32x4 acc[4][4] = {};

  const char* Xb = (const char*)X;
  const char* Wb = (const char*)W;
  char* XsB = (char*)&Xs[0][0];
  char* WsB = (char*)&Ws[0][0];

  const int r_a = (wr << 6) + (lane & 15);
  const int r_b = (wc << 6) + (lane & 15);
  const int kh = (lane >> 4) * 16;  // byte offset of this lane's k-slot group

  for (int ks = 0; ks < KP / 32; ++ks) {
    // stage 8KB X-tile + 8KB W-tile: chunk c (16B) -> row c>>2, part c&3
    {
      int c = tid;
      gl_lds16(Xb + (size_t)(m0 + (c >> 2)) * (KP * 2) + (size_t)ks * 64 + (c & 3) * 16,
               XsB + (wid << 10));
      gl_lds16(Wb + (size_t)(j0 + (c >> 2)) * (KP * 2) + (size_t)ks * 64 + (c & 3) * 16,
               WsB + (wid << 10));
      c = tid + 256;
      gl_lds16(Xb + (size_t)(m0 + (c >> 2)) * (KP * 2) + (size_t)ks * 64 + (c & 3) * 16,
               XsB + 4096 + (wid << 10));
      gl_lds16(Wb + (size_t)(j0 + (c >> 2)) * (KP * 2) + (size_t)ks * 64 + (c & 3) * 16,
               WsB + 4096 + (wid << 10));
    }
    __syncthreads();  // compiler emits vmcnt(0) drain before barrier
    bf16x8 a[4], b[4];
#pragma unroll
    for (int mf = 0; mf < 4; ++mf)
      a[mf] = *(const bf16x8*)(XsB + (size_t)(r_a + mf * 16) * 64 + kh);
#pragma unroll
    for (int nf = 0; nf < 4; ++nf)
      b[nf] = *(const bf16x8*)(WsB + (size_t)(r_b + nf * 16) * 64 + kh);
#pragma unroll
    for (int mf = 0; mf < 4; ++mf)
#pragma unroll
      for (int nf = 0; nf < 4; ++nf)
        acc[mf][nf] = __builtin_amdgcn_mfma_f32_16x16x32_bf16(a[mf], b[nf], acc[mf][nf], 0, 0, 0);
    __syncthreads();
  }

  // epilogue: C/D layout col=lane&15, row=(lane>>4)*4+reg (m89-verified)
  const int rr = (lane >> 4) << 2;
  const int cc = lane & 15;
#pragma unroll
  for (int mf = 0; mf < 4; ++mf) {
#pragma unroll
    for (int nf = 0; nf < 4; ++nf) {
      int col = j0 + (wc << 6) + nf * 16 + cc;
#pragma unroll
      for (int r = 0; r < 4; ++r) {
        int row = m0 + (wr << 6) + mf * 16 + rr + r;
        H[(size_t)row * J + col] = __float2bfloat16(acc[mf][nf][r]);
      }
    }
  }
}

// ---------------- expert blend + bias + activation ----------------
__device__ __forceinline__ void storev(float* p, float v) { *p = v; }
__device__ __forceinline__ void storev(__hip_bfloat16* p, float v) { *p = __float2bfloat16(v); }

template <bool ELU, typename OT>
__global__ void blend_k(const __hip_bfloat16* __restrict__ H, const float* __restrict__ coeff,
                        const float* __restrict__ bias, OT* __restrict__ Y,
                        int OUT_PAD, int OUT_eff, int ldY, int bias_ld, int J)
{
  int n = blockIdx.y;
  int o = blockIdx.x * 256 + threadIdx.x;
  if (o >= OUT_eff) return;
  const __hip_bfloat16* h = H + (size_t)n * J + o;
  float s = 0.f;
#pragma unroll
  for (int e = 0; e < 8; ++e) {
    float hv = __bfloat162float(h[(size_t)e * OUT_PAD]);
    float bv = bias[e * bias_ld + o];
    s += coeff[(size_t)n * 8 + e] * (hv + bv);
  }
  if (ELU) s = s > 0.f ? s : expm1f(s);
  storev(&Y[(size_t)n * ldY + o], s);
}

// ---------------- launch ----------------
extern "C" void kernel_launch(void* const* d_in, const int* in_sizes, int n_in,
                              void* d_out, int out_size, void* d_ws, size_t ws_size,
                              hipStream_t stream)
{
  const float* latent    = (const float*)d_in[0];
  const float* condition = (const float*)d_in[1];
  const float* phase     = (const float*)d_in[2];
  const float* gw1 = (const float*)d_in[3];
  const float* gb1 = (const float*)d_in[4];
  const float* gw2 = (const float*)d_in[5];
  const float* gb2 = (const float*)d_in[6];
  const float* gw3 = (const float*)d_in[7];
  const float* gb3 = (const float*)d_in[8];
  const float* w0  = (const float*)d_in[9];
  const float* b0  = (const float*)d_in[10];
  const float* w1  = (const float*)d_in[11];
  const float* b1  = (const float*)d_in[12];
  const float* w2  = (const float*)d_in[13];
  const float* b2  = (const float*)d_in[14];

  float* out   = (float*)d_out;
  float* coeff = out + (size_t)NR * 171;  // output 1 region; also consumed by blends

  char* ws = (char*)d_ws;
  __hip_bfloat16* wt0 = (__hip_bfloat16*)ws; ws += (size_t)8 * 512 * 288 * 2;
  __hip_bfloat16* wt1 = (__hip_bfloat16*)ws; ws += (size_t)8 * 512 * 576 * 2;
  __hip_bfloat16* wt2 = (__hip_bfloat16*)ws; ws += (size_t)8 * 192 * 512 * 2;
  __hip_bfloat16* x0  = (__hip_bfloat16*)ws; ws += (size_t)NR * 288 * 2;
  __hip_bfloat16* x1  = (__hip_bfloat16*)ws; ws += (size_t)NR * 576 * 2;
  __hip_bfloat16* x2  = (__hip_bfloat16*)ws; ws += (size_t)NR * 512 * 2;
  __hip_bfloat16* Hbf = (__hip_bfloat16*)ws; ws += (size_t)NR * 4096 * 2;

  // prep: weight transposes (fp32 -> bf16, [E][OP][KP]) + padded inputs + gate
  transpose_cvt<<<dim3(9, 16, 8),  256, 0, stream>>>(w0, wt0, 283, 512, 288, 512);
  transpose_cvt<<<dim3(18, 16, 8), 256, 0, stream>>>(w1, wt1, 576, 512, 576, 512);
  transpose_cvt<<<dim3(16, 6, 8),  256, 0, stream>>>(w2, wt2, 512, 171, 512, 192);
  build_x<<<(NR * 352 + 255) / 256, 256, 0, stream>>>(condition, latent, x0, x1);
  gate_kernel<<<256, 128, 0, stream>>>(phase, latent, gw1, gb1, gw2, gb2, gw3, gb3, coeff);

  // layer 0: [NR,288] x [288, 8*512] -> H ; blend+elu -> x1[:, :512]
  gemm_bf16<288><<<dim3(32, 32), 256, 0, stream>>>(x0, wt0, Hbf, 4096);
  blend_k<true, __hip_bfloat16><<<dim3(2, NR), 256, 0, stream>>>(Hbf, coeff, b0, x1, 512, 512, 576, 512, 4096);

  // layer 1: [NR,576] x [576, 8*512] -> H ; blend+elu -> x2
  gemm_bf16<576><<<dim3(32, 32), 256, 0, stream>>>(x1, wt1, Hbf, 4096);
  blend_k<true, __hip_bfloat16><<<dim3(2, NR), 256, 0, stream>>>(Hbf, coeff, b1, x2, 512, 512, 512, 512, 4096);

  // layer 2: [NR,512] x [512, 8*192] -> H ; blend (no act) -> d_out fp32 [NR,171]
  gemm_bf16<512><<<dim3(32, 12), 256, 0, stream>>>(x2, wt2, Hbf, 1536);
  blend_k<false, float><<<dim3(1, NR), 256, 0, stream>>>(Hbf, coeff, b2, out, 192, 171, 171, 171, 1536);
}

// Round 2
// 135.083 us; speedup vs baseline: 1.0073x; 1.0073x over previous
//
#include <hip/hip_runtime.h>
#include <hip/hip_bf16.h>

#define NR 4096

typedef float f32x4 __attribute__((ext_vector_type(4)));
typedef __bf16 bf16x8 __attribute__((ext_vector_type(8)));

typedef __attribute__((address_space(1))) unsigned int u32_g;
typedef __attribute__((address_space(3))) unsigned int u32_l;

__device__ __forceinline__ void gl_lds16(const void* g, void* l) {
  // global -> LDS direct copy, 16B per lane; LDS dest = wave-uniform base + lane*16
  __builtin_amdgcn_global_load_lds((const u32_g*)g, (u32_l*)l, 16, 0, 0);
}

// =====================================================================
// Staged operand layout (both A-activations and B-weights), bf16:
//   logical Z[rows][K], row-blocks RB of 256 rows, K-tiles T of 64:
//   16B chunk of element (row,k):
//     off = ((RB*KT + T)*2 + s)*16384 + g*4096 + (row&255)*16 + e*2
//   where kk=k&63, s=kk>>5, g=(kk>>3)&3, e=k&7.
//   => GEMM staging reads are LINEAR, LDS frag reads are CONFLICT-FREE.
// =====================================================================

// ---------------- weight transpose+stage: fp32 [E][Kin][512] -> staged B' ----
__global__ __launch_bounds__(256) void stage_w(const float* __restrict__ w,
                                               __hip_bfloat16* __restrict__ out,
                                               int Kin, int KT)
{
  __shared__ float t[64][65];
  int k0 = blockIdx.x * 64;          // gridDim.x = KT
  int j0 = blockIdx.y * 64;          // gridDim.y = 64 (J = 4096 = 8 experts * 512)
  int e = j0 >> 9, o0 = j0 & 511;
  int tid = threadIdx.x;
  int tx = tid & 63, ty = tid >> 6;  // 64 x 4
#pragma unroll
  for (int i = 0; i < 16; ++i) {
    int k = k0 + ty + i * 4;
    float v = (k < Kin) ? w[((size_t)e * Kin + k) * 512 + o0 + tx] : 0.f;
    t[ty + i * 4][tx] = v;
  }
  __syncthreads();
#pragma unroll
  for (int i2 = 0; i2 < 2; ++i2) {
    int c = i2 * 256 + tid;
    int j = c & 63, sg = c >> 6;     // sg = s*4+g, local k = sg*8 + e8
    bf16x8 v;
#pragma unroll
    for (int e8 = 0; e8 < 8; ++e8) v[e8] = (__bf16)t[sg * 8 + e8][j];
    int jg = j0 + j;
    size_t off = (((size_t)(jg >> 8) * KT + blockIdx.x) * 2 + (sg >> 2)) * 16384
               + (size_t)(sg & 3) * 4096 + (size_t)(jg & 255) * 16;
    *(bf16x8*)((char*)out + off) = v;
  }
}

// ---------------- x0 staged build: [cond(219)|latent(64)|0] KP=320, KT=5 ----
__global__ void stage_x0(const float* __restrict__ cond, const float* __restrict__ lat,
                         __hip_bfloat16* __restrict__ out)
{
  int c = blockIdx.x * 256 + threadIdx.x;  // 163840 chunks total
  int RB = c / 10240;                      // 5 tiles * 2048 chunks
  int r1 = c - RB * 10240;
  int T = r1 >> 11;
  int r2 = r1 & 2047;
  int n = RB * 256 + (r2 & 255);
  int k0 = T * 64 + (r2 >> 10) * 32 + ((r2 >> 8) & 3) * 8;
  bf16x8 v;
#pragma unroll
  for (int e = 0; e < 8; ++e) {
    int k = k0 + e;
    float f = (k < 219) ? cond[(size_t)n * 219 + k]
            : (k < 283) ? lat[(size_t)n * 64 + (k - 219)] : 0.f;
    v[e] = (__bf16)f;
  }
  *(bf16x8*)((char*)out + (size_t)c * 16) = v;  // enumeration == layout order
}

// ---------------- x1 staged: latent -> K-tile T=8 (k 512..575), KT=9 ----
__global__ void stage_lat1(const float* __restrict__ lat, __hip_bfloat16* __restrict__ out)
{
  int c = blockIdx.x * 256 + threadIdx.x;  // 32768 chunks
  int RB = c >> 11, r2 = c & 2047;
  int n = RB * 256 + (r2 & 255);
  int l0 = (r2 >> 10) * 32 + ((r2 >> 8) & 3) * 8;
  bf16x8 v;
#pragma unroll
  for (int e = 0; e < 8; ++e) v[e] = (__bf16)lat[(size_t)n * 64 + l0 + e];
  size_t off = ((size_t)RB * 9 + 8) * 32768 + (size_t)r2 * 16;
  *(bf16x8*)((char*)out + off) = v;
}

// ---------------- old-style weight transpose for layer 2 ----------------
__global__ void transpose_cvt(const float* __restrict__ in, __hip_bfloat16* __restrict__ out,
                              int Kin, int Oin, int KP, int OP)
{
  __shared__ float t[32][33];
  int e = blockIdx.z;
  int k0 = blockIdx.x * 32, o0 = blockIdx.y * 32;
  int tx = threadIdx.x & 31, ty = threadIdx.x >> 5;
#pragma unroll
  for (int i = 0; i < 4; ++i) {
    int k = k0 + ty + i * 8;
    int o = o0 + tx;
    float v = (k < Kin && o < Oin) ? in[((size_t)e * Kin + k) * Oin + o] : 0.f;
    t[ty + i * 8][tx] = v;
  }
  __syncthreads();
#pragma unroll
  for (int i = 0; i < 4; ++i) {
    int o = o0 + ty + i * 8;
    int k = k0 + tx;
    if (o < OP && k < KP)
      out[((size_t)e * OP + o) * KP + k] = __float2bfloat16(t[tx][ty + i * 8]);
  }
}

// ---------------- gate network (exact fp32) ----------------
__global__ __launch_bounds__(128) void gate_kernel(
    const float* __restrict__ phase, const float* __restrict__ latent,
    const float* __restrict__ w1, const float* __restrict__ b1,
    const float* __restrict__ w2, const float* __restrict__ b2,
    const float* __restrict__ w3, const float* __restrict__ b3,
    float* __restrict__ coeff_out)
{
  __shared__ float g0[16][104];
  __shared__ float h1[16][128];
  __shared__ float h2[16][129];
  __shared__ float lg[16][8];
  int n0 = blockIdx.x * 16;
  int t = threadIdx.x;

  for (int i = t; i < 16 * 104; i += 128) {
    int r = i / 104, c = i - r * 104;
    float v = (c < 40) ? phase[(size_t)(n0 + r) * 40 + c]
                       : latent[(size_t)(n0 + r) * 64 + (c - 40)];
    g0[r][c] = v;
  }
  __syncthreads();
  {
    float acc[16];
#pragma unroll
    for (int r = 0; r < 16; ++r) acc[r] = 0.f;
    for (int k = 0; k < 104; ++k) {
      float w = w1[k * 128 + t];
#pragma unroll
      for (int r = 0; r < 16; ++r) acc[r] += g0[r][k] * w;
    }
    float bb = b1[t];
#pragma unroll
    for (int r = 0; r < 16; ++r) { float v = acc[r] + bb; h1[r][t] = v > 0.f ? v : expm1f(v); }
  }
  __syncthreads();
  {
    float acc[16];
#pragma unroll
    for (int r = 0; r < 16; ++r) acc[r] = 0.f;
    for (int k = 0; k < 128; ++k) {
      float w = w2[k * 128 + t];
#pragma unroll
      for (int r = 0; r < 16; ++r) acc[r] += h1[r][k] * w;
    }
    float bb = b2[t];
#pragma unroll
    for (int r = 0; r < 16; ++r) { float v = acc[r] + bb; h2[r][t] = v > 0.f ? v : expm1f(v); }
  }
  __syncthreads();
  {
    int r = t >> 3, e = t & 7;
    float acc = 0.f;
    for (int k = 0; k < 128; ++k) acc += h2[r][k] * w3[k * 8 + e];
    lg[r][e] = acc + b3[e];
  }
  __syncthreads();
  if (t < 16) {
    float mx = lg[t][0];
#pragma unroll
    for (int e = 1; e < 8; ++e) mx = fmaxf(mx, lg[t][e]);
    float ex[8]; float s = 0.f;
#pragma unroll
    for (int e = 0; e < 8; ++e) { ex[e] = expf(lg[t][e] - mx); s += ex[e]; }
    float inv = 1.f / s;
#pragma unroll
    for (int e = 0; e < 8; ++e) coeff_out[(size_t)(n0 + t) * 8 + e] = ex[e] * inv;
  }
}

// =====================================================================
// 8-phase 256x256 GEMM, BK=64, 8 waves (2M x 4N), 512 threads.
// Staged A'/B' inputs (see layout above). LDS: 2 buf x (A 32KB + B 32KB).
// Counted vmcnt (never 0 mid-loop), raw barriers, setprio around MFMA.
// =====================================================================

#define MFMA_PHASE(NH)                                                                  \
  _Pragma("unroll") for (int fm = 0; fm < 8; ++fm) {                                    \
    acc[fm][2*(NH)]   = __builtin_amdgcn_mfma_f32_16x16x32_bf16(a[fm], b0, acc[fm][2*(NH)],   0, 0, 0); \
    acc[fm][2*(NH)+1] = __builtin_amdgcn_mfma_f32_16x16x32_bf16(a[fm], b1, acc[fm][2*(NH)+1], 0, 0, 0); \
  }

template <bool ST>
__device__ __forceinline__ void ktile(const char* cL, char* nL,
                                      const char* gA, const char* gB,
                                      int tid, int wid, int aoff, int boff,
                                      f32x4 (&acc)[8][4])
{
  bf16x8 a[8], b0, b1;
  const char* pa = cL;            // s=0 A half
  const char* pb = cL + 32768;    // s=0 B half
  // ---- P(0,0): read a(s=0), b0..1 ; stage A0(t+1)
#pragma unroll
  for (int fm = 0; fm < 8; ++fm) a[fm] = *(const bf16x8*)(pa + aoff + fm * 256);
  b0 = *(const bf16x8*)(pb + boff + 0);
  b1 = *(const bf16x8*)(pb + boff + 256);
  if (ST) {
    gl_lds16(gA + tid * 16,        nL + (wid << 10));
    gl_lds16(gA + 8192 + tid * 16, nL + 8192 + (wid << 10));
  }
  __builtin_amdgcn_s_barrier();
  __builtin_amdgcn_s_setprio(1);
  MFMA_PHASE(0);
  __builtin_amdgcn_s_setprio(0);
  __builtin_amdgcn_s_barrier();
  // ---- P(0,1): read b2..3 (s=0) ; stage B0(t+1) ; gate A1,B1(t)
  b0 = *(const bf16x8*)(pb + boff + 512);
  b1 = *(const bf16x8*)(pb + boff + 768);
  if (ST) {
    gl_lds16(gB + tid * 16,        nL + 32768 + (wid << 10));
    gl_lds16(gB + 8192 + tid * 16, nL + 32768 + 8192 + (wid << 10));
  }
  __builtin_amdgcn_s_barrier();
  __builtin_amdgcn_s_setprio(1);
  MFMA_PHASE(1);
  __builtin_amdgcn_s_setprio(0);
  if (ST) asm volatile("s_waitcnt vmcnt(4)" ::: "memory");
  else    asm volatile("s_waitcnt vmcnt(0)" ::: "memory");
  __builtin_amdgcn_s_barrier();
  // ---- P(1,0): read a(s=1), b0..1 ; stage A1(t+1)
  pa = cL + 16384; pb = cL + 32768 + 16384;
#pragma unroll
  for (int fm = 0; fm < 8; ++fm) a[fm] = *(const bf16x8*)(pa + aoff + fm * 256);
  b0 = *(const bf16x8*)(pb + boff + 0);
  b1 = *(const bf16x8*)(pb + boff + 256);
  if (ST) {
    gl_lds16(gA + 16384 + tid * 16,        nL + 16384 + (wid << 10));
    gl_lds16(gA + 16384 + 8192 + tid * 16, nL + 16384 + 8192 + (wid << 10));
  }
  __builtin_amdgcn_s_barrier();
  __builtin_amdgcn_s_setprio(1);
  MFMA_PHASE(0);
  __builtin_amdgcn_s_setprio(0);
  __builtin_amdgcn_s_barrier();
  // ---- P(1,1): read b2..3 (s=1) ; stage B1(t+1) ; gate A0,B0(t+1)
  b0 = *(const bf16x8*)(pb + boff + 512);
  b1 = *(const bf16x8*)(pb + boff + 768);
  if (ST) {
    gl_lds16(gB + 16384 + tid * 16,        nL + 32768 + 16384 + (wid << 10));
    gl_lds16(gB + 16384 + 8192 + tid * 16, nL + 32768 + 16384 + 8192 + (wid << 10));
  }
  __builtin_amdgcn_s_barrier();
  __builtin_amdgcn_s_setprio(1);
  MFMA_PHASE(1);
  __builtin_amdgcn_s_setprio(0);
  if (ST) asm volatile("s_waitcnt vmcnt(4)" ::: "memory");
  __builtin_amdgcn_s_barrier();
}

template <int KT>
__global__ __launch_bounds__(512, 2) void gemm8(const __hip_bfloat16* __restrict__ Ap,
                                                const __hip_bfloat16* __restrict__ Bp,
                                                __hip_bfloat16* __restrict__ H, int J)
{
  __shared__ __align__(16) char lds[131072];
  const int tid = threadIdx.x;
  const int lane = tid & 63;
  const int wid = tid >> 6;
  const int wr = wid >> 2, wc = wid & 3;     // 2 x 4 wave grid, wave tile 128x64
  const int l15 = lane & 15, lg = lane >> 4;
  const int aoff = lg * 4096 + wr * 2048 + l15 * 16;
  const int boff = lg * 4096 + wc * 1024 + l15 * 16;

  const char* aG = (const char*)Ap + (size_t)blockIdx.x * KT * 32768;
  const char* bG = (const char*)Bp + (size_t)blockIdx.y * KT * 32768;

  f32x4 acc[8][4] = {};

  // prologue: stage tile 0 (A0,B0,A1,B1), gate A0,B0
  {
    char* L = lds;
    gl_lds16(aG + tid * 16,                 L + (wid << 10));
    gl_lds16(aG + 8192 + tid * 16,          L + 8192 + (wid << 10));
    gl_lds16(bG + tid * 16,                 L + 32768 + (wid << 10));
    gl_lds16(bG + 8192 + tid * 16,          L + 32768 + 8192 + (wid << 10));
    gl_lds16(aG + 16384 + tid * 16,         L + 16384 + (wid << 10));
    gl_lds16(aG + 16384 + 8192 + tid * 16,  L + 16384 + 8192 + (wid << 10));
    gl_lds16(bG + 16384 + tid * 16,         L + 32768 + 16384 + (wid << 10));
    gl_lds16(bG + 16384 + 8192 + tid * 16,  L + 32768 + 16384 + 8192 + (wid << 10));
    asm volatile("s_waitcnt vmcnt(4)" ::: "memory");
    __builtin_amdgcn_s_barrier();
  }

  for (int t = 0; t < KT; ++t) {
    const char* cL = lds + ((t & 1) << 16);
    char* nL = lds + (((t + 1) & 1) << 16);
    const char* gA = aG + (size_t)(t + 1) * 32768;
    const char* gB = bG + (size_t)(t + 1) * 32768;
    if (t + 1 < KT) ktile<true>(cL, nL, gA, gB, tid, wid, aoff, boff, acc);
    else            ktile<false>(cL, nL, gA, gB, tid, wid, aoff, boff, acc);
  }

  // epilogue: C/D layout col=lane&15, row=(lane>>4)*4+reg (verified R1)
  const int rr = lg << 2;
  const int m_base = blockIdx.x * 256 + wr * 128;
  const int j_base = blockIdx.y * 256 + wc * 64;
#pragma unroll
  for (int fm = 0; fm < 8; ++fm) {
#pragma unroll
    for (int fn = 0; fn < 4; ++fn) {
      int col = j_base + fn * 16 + l15;
#pragma unroll
      for (int r = 0; r < 4; ++r) {
        int row = m_base + fm * 16 + rr + r;
        H[(size_t)row * J + col] = __float2bfloat16(acc[fm][fn][r]);
      }
    }
  }
}

// ---------------- 128^2 m97-style GEMM (kept for layer 2) ----------------
template <int KP>
__global__ __launch_bounds__(256) void gemm_bf16(const __hip_bfloat16* __restrict__ X,
                                                 const __hip_bfloat16* __restrict__ W,
                                                 __hip_bfloat16* __restrict__ H, int J)
{
  __shared__ __align__(16) __hip_bfloat16 Xs[128][32];
  __shared__ __align__(16) __hip_bfloat16 Ws[128][32];
  const int tid = threadIdx.x;
  const int lane = tid & 63;
  const int wid = tid >> 6;
  const int wr = wid >> 1, wc = wid & 1;
  const int m0 = blockIdx.x * 128;
  const int j0 = blockIdx.y * 128;

  f32x4 acc[4][4] = {};

  const char* Xb = (const char*)X;
  const char* Wb = (const char*)W;
  char* XsB = (char*)&Xs[0][0];
  char* WsB = (char*)&Ws[0][0];

  const int r_a = (wr << 6) + (lane & 15);
  const int r_b = (wc << 6) + (lane & 15);
  const int kh = (lane >> 4) * 16;

  for (int ks = 0; ks < KP / 32; ++ks) {
    {
      int c = tid;
      gl_lds16(Xb + (size_t)(m0 + (c >> 2)) * (KP * 2) + (size_t)ks * 64 + (c & 3) * 16,
               XsB + (wid << 10));
      gl_lds16(Wb + (size_t)(j0 + (c >> 2)) * (KP * 2) + (size_t)ks * 64 + (c & 3) * 16,
               WsB + (wid << 10));
      c = tid + 256;
      gl_lds16(Xb + (size_t)(m0 + (c >> 2)) * (KP * 2) + (size_t)ks * 64 + (c & 3) * 16,
               XsB + 4096 + (wid << 10));
      gl_lds16(Wb + (size_t)(j0 + (c >> 2)) * (KP * 2) + (size_t)ks * 64 + (c & 3) * 16,
               WsB + 4096 + (wid << 10));
    }
    __syncthreads();
    bf16x8 a[4], b[4];
#pragma unroll
    for (int mf = 0; mf < 4; ++mf)
      a[mf] = *(const bf16x8*)(XsB + (size_t)(r_a + mf * 16) * 64 + kh);
#pragma unroll
    for (int nf = 0; nf < 4; ++nf)
      b[nf] = *(const bf16x8*)(WsB + (size_t)(r_b + nf * 16) * 64 + kh);
#pragma unroll
    for (int mf = 0; mf < 4; ++mf)
#pragma unroll
      for (int nf = 0; nf < 4; ++nf)
        acc[mf][nf] = __builtin_amdgcn_mfma_f32_16x16x32_bf16(a[mf], b[nf], acc[mf][nf], 0, 0, 0);
    __syncthreads();
  }

  const int rr = (lane >> 4) << 2;
  const int cc = lane & 15;
#pragma unroll
  for (int mf = 0; mf < 4; ++mf) {
#pragma unroll
    for (int nf = 0; nf < 4; ++nf) {
      int col = j0 + (wc << 6) + nf * 16 + cc;
#pragma unroll
      for (int r = 0; r < 4; ++r) {
        int row = m0 + (wr << 6) + mf * 16 + rr + r;
        H[(size_t)row * J + col] = __float2bfloat16(acc[mf][nf][r]);
      }
    }
  }
}

// ---------------- vectorized blends ----------------
// blend0: H[n][e*512+o] -> elu(sum_e c*(h+b)) -> x1' STAGED (KT=9, k=o)
__global__ __launch_bounds__(256) void blend0v(const __hip_bfloat16* __restrict__ H,
                                               const float* __restrict__ coeff,
                                               const float* __restrict__ bias,
                                               __hip_bfloat16* __restrict__ Xs)
{
  int tid = threadIdx.x;
  int o8 = tid & 63, nl = tid >> 6;
  int n = blockIdx.x * 4 + nl;
  const bf16x8* h = (const bf16x8*)(H + (size_t)n * 4096) + o8;
  float s[8] = {0.f, 0.f, 0.f, 0.f, 0.f, 0.f, 0.f, 0.f};
#pragma unroll
  for (int e = 0; e < 8; ++e) {
    bf16x8 hv = h[e * 64];
    float c = coeff[(size_t)n * 8 + e];
    const float4* bp = (const float4*)(bias + e * 512 + o8 * 8);
    float4 bv0 = bp[0], bv1 = bp[1];
    s[0] += c * ((float)hv[0] + bv0.x); s[1] += c * ((float)hv[1] + bv0.y);
    s[2] += c * ((float)hv[2] + bv0.z); s[3] += c * ((float)hv[3] + bv0.w);
    s[4] += c * ((float)hv[4] + bv1.x); s[5] += c * ((float)hv[5] + bv1.y);
    s[6] += c * ((float)hv[6] + bv1.z); s[7] += c * ((float)hv[7] + bv1.w);
  }
  bf16x8 v;
#pragma unroll
  for (int j = 0; j < 8; ++j) {
    float x = s[j];
    x = x > 0.f ? x : expm1f(x);
    v[j] = (__bf16)x;
  }
  int T = o8 >> 3, s_ = (o8 >> 2) & 1, g = o8 & 3;
  size_t off = (((size_t)(n >> 8) * 9 + T) * 2 + s_) * 16384
             + (size_t)g * 4096 + (size_t)(n & 255) * 16;
  *(bf16x8*)((char*)Xs + off) = v;
}

// blend1: -> x2 row-major [NR][512] bf16
__global__ __launch_bounds__(256) void blend1v(const __hip_bfloat16* __restrict__ H,
                                               const float* __restrict__ coeff,
                                               const float* __restrict__ bias,
                                               __hip_bfloat16* __restrict__ x2)
{
  int tid = threadIdx.x;
  int o8 = tid & 63, nl = tid >> 6;
  int n = blockIdx.x * 4 + nl;
  const bf16x8* h = (const bf16x8*)(H + (size_t)n * 4096) + o8;
  float s[8] = {0.f, 0.f, 0.f, 0.f, 0.f, 0.f, 0.f, 0.f};
#pragma unroll
  for (int e = 0; e < 8; ++e) {
    bf16x8 hv = h[e * 64];
    float c = coeff[(size_t)n * 8 + e];
    const float4* bp = (const float4*)(bias + e * 512 + o8 * 8);
    float4 bv0 = bp[0], bv1 = bp[1];
    s[0] += c * ((float)hv[0] + bv0.x); s[1] += c * ((float)hv[1] + bv0.y);
    s[2] += c * ((float)hv[2] + bv0.z); s[3] += c * ((float)hv[3] + bv0.w);
    s[4] += c * ((float)hv[4] + bv1.x); s[5] += c * ((float)hv[5] + bv1.y);
    s[6] += c * ((float)hv[6] + bv1.z); s[7] += c * ((float)hv[7] + bv1.w);
  }
  bf16x8 v;
#pragma unroll
  for (int j = 0; j < 8; ++j) {
    float x = s[j];
    x = x > 0.f ? x : expm1f(x);
    v[j] = (__bf16)x;
  }
  ((bf16x8*)(x2 + (size_t)n * 512))[o8] = v;
}

// blend2: final, fp32 out [NR][171]
__global__ void blend2_k(const __hip_bfloat16* __restrict__ H, const float* __restrict__ coeff,
                         const float* __restrict__ bias, float* __restrict__ Y)
{
  int n = blockIdx.y;
  int o = blockIdx.x * 256 + threadIdx.x;
  if (o >= 171) return;
  const __hip_bfloat16* h = H + (size_t)n * 1536 + o;
  float s = 0.f;
#pragma unroll
  for (int e = 0; e < 8; ++e) {
    float hv = __bfloat162float(h[(size_t)e * 192]);
    float bv = bias[e * 171 + o];
    s += coeff[(size_t)n * 8 + e] * (hv + bv);
  }
  Y[(size_t)n * 171 + o] = s;
}

// ---------------- launch ----------------
extern "C" void kernel_launch(void* const* d_in, const int* in_sizes, int n_in,
                              void* d_out, int out_size, void* d_ws, size_t ws_size,
                              hipStream_t stream)
{
  const float* latent    = (const float*)d_in[0];
  const float* condition = (const float*)d_in[1];
  const float* phase     = (const float*)d_in[2];
  const float* gw1 = (const float*)d_in[3];
  const float* gb1 = (const float*)d_in[4];
  const float* gw2 = (const float*)d_in[5];
  const float* gb2 = (const float*)d_in[6];
  const float* gw3 = (const float*)d_in[7];
  const float* gb3 = (const float*)d_in[8];
  const float* w0  = (const float*)d_in[9];
  const float* b0  = (const float*)d_in[10];
  const float* w1  = (const float*)d_in[11];
  const float* b1  = (const float*)d_in[12];
  const float* w2  = (const float*)d_in[13];
  const float* b2  = (const float*)d_in[14];

  float* out   = (float*)d_out;
  float* coeff = out + (size_t)NR * 171;  // coeff is output 1

  char* ws = (char*)d_ws;
  __hip_bfloat16* x0s  = (__hip_bfloat16*)ws; ws += (size_t)16 * 5 * 32768;   // 2.6 MB
  __hip_bfloat16* x1s  = (__hip_bfloat16*)ws; ws += (size_t)16 * 9 * 32768;   // 4.7 MB
  __hip_bfloat16* wt0s = (__hip_bfloat16*)ws; ws += (size_t)16 * 5 * 32768;
  __hip_bfloat16* wt1s = (__hip_bfloat16*)ws; ws += (size_t)16 * 9 * 32768;
  __hip_bfloat16* wt2  = (__hip_bfloat16*)ws; ws += (size_t)1536 * 512 * 2;
  __hip_bfloat16* x2   = (__hip_bfloat16*)ws; ws += (size_t)NR * 512 * 2;
  __hip_bfloat16* Hbf  = (__hip_bfloat16*)ws; ws += (size_t)NR * 4096 * 2;

  // prep
  stage_w<<<dim3(5, 64), 256, 0, stream>>>(w0, wt0s, 283, 5);
  stage_w<<<dim3(9, 64), 256, 0, stream>>>(w1, wt1s, 576, 9);
  transpose_cvt<<<dim3(16, 6, 8), 256, 0, stream>>>(w2, wt2, 512, 171, 512, 192);
  stage_x0<<<640, 256, 0, stream>>>(condition, latent, x0s);
  stage_lat1<<<128, 256, 0, stream>>>(latent, x1s);
  gate_kernel<<<256, 128, 0, stream>>>(phase, latent, gw1, gb1, gw2, gb2, gw3, gb3, coeff);

  // layer 0: [4096,320]x[320,4096] staged 8-phase
  gemm8<5><<<dim3(16, 16), 512, 0, stream>>>(x0s, wt0s, Hbf, 4096);
  blend0v<<<1024, 256, 0, stream>>>(Hbf, coeff, b0, x1s);

  // layer 1: [4096,576]x[576,4096] staged 8-phase
  gemm8<9><<<dim3(16, 16), 512, 0, stream>>>(x1s, wt1s, Hbf, 4096);
  blend1v<<<1024, 256, 0, stream>>>(Hbf, coeff, b1, x2);

  // layer 2: [4096,512]x[512,1536] classic 128^2
  gemm_bf16<512><<<dim3(32, 12), 256, 0, stream>>>(x2, wt2, Hbf, 1536);
  blend2_k<<<dim3(1, NR), 256, 0, stream>>>(Hbf, coeff, b2, out);
}

// Round 3
// 134.902 us; speedup vs baseline: 1.0087x; 1.0013x over previous
//
#include <hip/hip_runtime.h>
#include <hip/hip_bf16.h>

#define NR 4096

typedef float f32x4 __attribute__((ext_vector_type(4)));
typedef __bf16 bf16x8 __attribute__((ext_vector_type(8)));

typedef __attribute__((address_space(1))) unsigned int u32_g;
typedef __attribute__((address_space(3))) unsigned int u32_l;

__device__ __forceinline__ void gl_lds16(const void* g, void* l) {
  __builtin_amdgcn_global_load_lds((const u32_g*)g, (u32_l*)l, 16, 0, 0);
}

// =====================================================================
// Staged operand layout (A-activations and B-weights), bf16:
//   logical Z[rows][K], row-blocks RB of 256, K-tiles T of 64:
//   16B chunk (row,k):  off = ((RB*KT + T)*2 + s)*16384 + g*4096 + (row&255)*16 + e*2
//   (kk=k&63, s=kk>>5, g=(kk>>3)&3, e=k&7)
// B columns are EXPERT-INTERLEAVED: GEMM col p <-> (o, e):
//   p = (o>>5)*256 + ((o>>3)&3)*64 + (e>>1)*16 + (o&7)*2 + (e&1)
//   => in-tile: e = fn*2 + (l15&1), o = by*32 + wc*8 + (l15>>1)
//   so the expert blend reduces over fn (in-lane) + one shfl_xor(1).
// =====================================================================

// ---- weight stage: fp32 [E][Kin][Oin] -> staged, expert-interleaved ----
__global__ __launch_bounds__(256) void stage_w(const float* __restrict__ w,
                                               __hip_bfloat16* __restrict__ out,
                                               int Kin, int KT, int Oin, int Opad)
{
  __shared__ float t[64][65];
  int oblk = Opad >> 6;
  int e = blockIdx.y / oblk;
  int o0 = (blockIdx.y % oblk) << 6;
  int k0 = blockIdx.x * 64;
  int tid = threadIdx.x;
  int tx = tid & 63, ty = tid >> 6;
#pragma unroll
  for (int i = 0; i < 16; ++i) {
    int k = k0 + ty + i * 4;
    int o = o0 + tx;
    float v = (k < Kin && o < Oin) ? w[((size_t)e * Kin + k) * Oin + o] : 0.f;
    t[ty + i * 4][tx] = v;
  }
  __syncthreads();
#pragma unroll
  for (int i2 = 0; i2 < 2; ++i2) {
    int c = i2 * 256 + tid;
    int j = c & 63, sg = c >> 6;   // local k = sg*8 + e8
    bf16x8 v;
#pragma unroll
    for (int e8 = 0; e8 < 8; ++e8) v[e8] = (__bf16)t[sg * 8 + e8][j];
    int o = o0 + j;
    int p = ((o >> 5) << 8) + (((o >> 3) & 3) << 6) + ((e >> 1) << 4) + ((o & 7) << 1) + (e & 1);
    size_t off = (((size_t)(p >> 8) * KT + blockIdx.x) * 2 + (sg >> 2)) * 16384
               + (size_t)(sg & 3) * 4096 + (size_t)(p & 255) * 16;
    *(bf16x8*)((char*)out + off) = v;
  }
}

// ---- x0 staged build: [cond(219)|latent(64)|0] K=320, KT=5 ----
__global__ void stage_x0(const float* __restrict__ cond, const float* __restrict__ lat,
                         __hip_bfloat16* __restrict__ out)
{
  int c = blockIdx.x * 256 + threadIdx.x;  // 163840 chunks
  int RB = c / 10240;
  int r1 = c - RB * 10240;
  int T = r1 >> 11;
  int r2 = r1 & 2047;
  int n = RB * 256 + (r2 & 255);
  int k0 = T * 64 + (r2 >> 10) * 32 + ((r2 >> 8) & 3) * 8;
  bf16x8 v;
#pragma unroll
  for (int e = 0; e < 8; ++e) {
    int k = k0 + e;
    float f = (k < 219) ? cond[(size_t)n * 219 + k]
            : (k < 283) ? lat[(size_t)n * 64 + (k - 219)] : 0.f;
    v[e] = (__bf16)f;
  }
  *(bf16x8*)((char*)out + (size_t)c * 16) = v;
}

// ---- restage y0 [4096,512] bf16 + latent -> x1s staged (KT=9) ----
__global__ void restage_y1(const __hip_bfloat16* __restrict__ y0,
                           const float* __restrict__ lat,
                           __hip_bfloat16* __restrict__ out)
{
  int c = blockIdx.x * 256 + threadIdx.x;  // 16*9*2048 = 294912
  int RB = c / 18432;
  int r1 = c - RB * 18432;
  int T = r1 >> 11;
  int r2 = r1 & 2047;
  int n = RB * 256 + (r2 & 255);
  int k0 = T * 64 + (r2 >> 10) * 32 + ((r2 >> 8) & 3) * 8;
  bf16x8 v;
  if (k0 < 512) {
    v = *(const bf16x8*)(y0 + (size_t)n * 512 + k0);
  } else {
#pragma unroll
    for (int e = 0; e < 8; ++e) v[e] = (__bf16)lat[(size_t)n * 64 + (k0 - 512) + e];
  }
  *(bf16x8*)((char*)out + (size_t)c * 16) = v;
}

// ---- restage y1 [4096,512] bf16 -> x2s staged (KT=8) ----
__global__ void restage_y2(const __hip_bfloat16* __restrict__ y1,
                           __hip_bfloat16* __restrict__ out)
{
  int c = blockIdx.x * 256 + threadIdx.x;  // 16*8*2048 = 262144
  int RB = c >> 14;
  int r1 = c & 16383;
  int T = r1 >> 11;
  int r2 = r1 & 2047;
  int n = RB * 256 + (r2 & 255);
  int k0 = T * 64 + (r2 >> 10) * 32 + ((r2 >> 8) & 3) * 8;
  bf16x8 v = *(const bf16x8*)(y1 + (size_t)n * 512 + k0);
  *(bf16x8*)((char*)out + (size_t)c * 16) = v;
}

// ---- gate network (exact fp32) ----
__global__ __launch_bounds__(128) void gate_kernel(
    const float* __restrict__ phase, const float* __restrict__ latent,
    const float* __restrict__ w1, const float* __restrict__ b1,
    const float* __restrict__ w2, const float* __restrict__ b2,
    const float* __restrict__ w3, const float* __restrict__ b3,
    float* __restrict__ coeff_out)
{
  __shared__ float g0[16][104];
  __shared__ float h1[16][128];
  __shared__ float h2[16][129];
  __shared__ float lg[16][8];
  int n0 = blockIdx.x * 16;
  int t = threadIdx.x;

  for (int i = t; i < 16 * 104; i += 128) {
    int r = i / 104, c = i - r * 104;
    float v = (c < 40) ? phase[(size_t)(n0 + r) * 40 + c]
                       : latent[(size_t)(n0 + r) * 64 + (c - 40)];
    g0[r][c] = v;
  }
  __syncthreads();
  {
    float acc[16];
#pragma unroll
    for (int r = 0; r < 16; ++r) acc[r] = 0.f;
    for (int k = 0; k < 104; ++k) {
      float w = w1[k * 128 + t];
#pragma unroll
      for (int r = 0; r < 16; ++r) acc[r] += g0[r][k] * w;
    }
    float bb = b1[t];
#pragma unroll
    for (int r = 0; r < 16; ++r) { float v = acc[r] + bb; h1[r][t] = v > 0.f ? v : expm1f(v); }
  }
  __syncthreads();
  {
    float acc[16];
#pragma unroll
    for (int r = 0; r < 16; ++r) acc[r] = 0.f;
    for (int k = 0; k < 128; ++k) {
      float w = w2[k * 128 + t];
#pragma unroll
      for (int r = 0; r < 16; ++r) acc[r] += h1[r][k] * w;
    }
    float bb = b2[t];
#pragma unroll
    for (int r = 0; r < 16; ++r) { float v = acc[r] + bb; h2[r][t] = v > 0.f ? v : expm1f(v); }
  }
  __syncthreads();
  {
    int r = t >> 3, e = t & 7;
    float acc = 0.f;
    for (int k = 0; k < 128; ++k) acc += h2[r][k] * w3[k * 8 + e];
    lg[r][e] = acc + b3[e];
  }
  __syncthreads();
  if (t < 16) {
    float mx = lg[t][0];
#pragma unroll
    for (int e = 1; e < 8; ++e) mx = fmaxf(mx, lg[t][e]);
    float ex[8]; float s = 0.f;
#pragma unroll
    for (int e = 0; e < 8; ++e) { ex[e] = expf(lg[t][e] - mx); s += ex[e]; }
    float inv = 1.f / s;
#pragma unroll
    for (int e = 0; e < 8; ++e) coeff_out[(size_t)(n0 + t) * 8 + e] = ex[e] * inv;
  }
}

// =====================================================================
// 8-phase 256x256 GEMM + FUSED expert-blend epilogue.
// =====================================================================

#define MFMA_PHASE(NH)                                                                  \
  _Pragma("unroll") for (int fm = 0; fm < 8; ++fm) {                                    \
    acc[fm][2*(NH)]   = __builtin_amdgcn_mfma_f32_16x16x32_bf16(a[fm], b0, acc[fm][2*(NH)],   0, 0, 0); \
    acc[fm][2*(NH)+1] = __builtin_amdgcn_mfma_f32_16x16x32_bf16(a[fm], b1, acc[fm][2*(NH)+1], 0, 0, 0); \
  }

template <bool ST>
__device__ __forceinline__ void ktile(const char* cL, char* nL,
                                      const char* gA, const char* gB,
                                      int tid, int wid, int aoff, int boff,
                                      f32x4 (&acc)[8][4])
{
  bf16x8 a[8], b0, b1;
  const char* pa = cL;
  const char* pb = cL + 32768;
  // P(0,0)
#pragma unroll
  for (int fm = 0; fm < 8; ++fm) a[fm] = *(const bf16x8*)(pa + aoff + fm * 256);
  b0 = *(const bf16x8*)(pb + boff + 0);
  b1 = *(const bf16x8*)(pb + boff + 256);
  if (ST) {
    gl_lds16(gA + tid * 16,        nL + (wid << 10));
    gl_lds16(gA + 8192 + tid * 16, nL + 8192 + (wid << 10));
  }
  __builtin_amdgcn_s_barrier();
  __builtin_amdgcn_s_setprio(1);
  MFMA_PHASE(0);
  __builtin_amdgcn_s_setprio(0);
  __builtin_amdgcn_s_barrier();
  // P(0,1)
  b0 = *(const bf16x8*)(pb + boff + 512);
  b1 = *(const bf16x8*)(pb + boff + 768);
  if (ST) {
    gl_lds16(gB + tid * 16,        nL + 32768 + (wid << 10));
    gl_lds16(gB + 8192 + tid * 16, nL + 32768 + 8192 + (wid << 10));
  }
  __builtin_amdgcn_s_barrier();
  __builtin_amdgcn_s_setprio(1);
  MFMA_PHASE(1);
  __builtin_amdgcn_s_setprio(0);
  if (ST) asm volatile("s_waitcnt vmcnt(4)" ::: "memory");
  else    asm volatile("s_waitcnt vmcnt(0)" ::: "memory");
  __builtin_amdgcn_s_barrier();
  // P(1,0)
  pa = cL + 16384; pb = cL + 32768 + 16384;
#pragma unroll
  for (int fm = 0; fm < 8; ++fm) a[fm] = *(const bf16x8*)(pa + aoff + fm * 256);
  b0 = *(const bf16x8*)(pb + boff + 0);
  b1 = *(const bf16x8*)(pb + boff + 256);
  if (ST) {
    gl_lds16(gA + 16384 + tid * 16,        nL + 16384 + (wid << 10));
    gl_lds16(gA + 16384 + 8192 + tid * 16, nL + 16384 + 8192 + (wid << 10));
  }
  __builtin_amdgcn_s_barrier();
  __builtin_amdgcn_s_setprio(1);
  MFMA_PHASE(0);
  __builtin_amdgcn_s_setprio(0);
  __builtin_amdgcn_s_barrier();
  // P(1,1)
  b0 = *(const bf16x8*)(pb + boff + 512);
  b1 = *(const bf16x8*)(pb + boff + 768);
  if (ST) {
    gl_lds16(gB + 16384 + tid * 16,        nL + 32768 + 16384 + (wid << 10));
    gl_lds16(gB + 16384 + 8192 + tid * 16, nL + 32768 + 16384 + 8192 + (wid << 10));
  }
  __builtin_amdgcn_s_barrier();
  __builtin_amdgcn_s_setprio(1);
  MFMA_PHASE(1);
  __builtin_amdgcn_s_setprio(0);
  if (ST) asm volatile("s_waitcnt vmcnt(4)" ::: "memory");
  __builtin_amdgcn_s_barrier();
}

__device__ __forceinline__ void storev(float* p, float v) { *p = v; }
__device__ __forceinline__ void storev(__hip_bfloat16* p, float v) { *p = __float2bfloat16(v); }

template <int KT, bool ELU, typename OT>
__global__ __launch_bounds__(512, 2) void gemm8(const __hip_bfloat16* __restrict__ Ap,
                                                const __hip_bfloat16* __restrict__ Bp,
                                                const float* __restrict__ coeff,
                                                const float* __restrict__ bias,
                                                OT* __restrict__ Y,
                                                int bias_ld, int ldY, int Oeff)
{
  __shared__ __align__(16) char lds[131072];
  const int tid = threadIdx.x;
  const int lane = tid & 63;
  const int wid = tid >> 6;
  const int wr = wid >> 2, wc = wid & 3;
  const int l15 = lane & 15, lg = lane >> 4;
  const int aoff = lg * 4096 + wr * 2048 + l15 * 16;
  const int boff = lg * 4096 + wc * 1024 + l15 * 16;

  const char* aG = (const char*)Ap + (size_t)blockIdx.x * KT * 32768;
  const char* bG = (const char*)Bp + (size_t)blockIdx.y * KT * 32768;

  f32x4 acc[8][4] = {};

  {
    char* L = lds;
    gl_lds16(aG + tid * 16,                 L + (wid << 10));
    gl_lds16(aG + 8192 + tid * 16,          L + 8192 + (wid << 10));
    gl_lds16(bG + tid * 16,                 L + 32768 + (wid << 10));
    gl_lds16(bG + 8192 + tid * 16,          L + 32768 + 8192 + (wid << 10));
    gl_lds16(aG + 16384 + tid * 16,         L + 16384 + (wid << 10));
    gl_lds16(aG + 16384 + 8192 + tid * 16,  L + 16384 + 8192 + (wid << 10));
    gl_lds16(bG + 16384 + tid * 16,         L + 32768 + 16384 + (wid << 10));
    gl_lds16(bG + 16384 + 8192 + tid * 16,  L + 32768 + 16384 + 8192 + (wid << 10));
    asm volatile("s_waitcnt vmcnt(4)" ::: "memory");
    __builtin_amdgcn_s_barrier();
  }

  for (int t = 0; t < KT; ++t) {
    const char* cL = lds + ((t & 1) << 16);
    char* nL = lds + (((t + 1) & 1) << 16);
    const char* gA = aG + (size_t)(t + 1) * 32768;
    const char* gB = bG + (size_t)(t + 1) * 32768;
    if (t + 1 < KT) ktile<true>(cL, nL, gA, gB, tid, wid, aoff, boff, acc);
    else            ktile<false>(cL, nL, gA, gB, tid, wid, aoff, boff, acc);
  }

  // ---- fused expert-blend epilogue ----
  // col p_local = wc*64 + fn*16 + l15  <->  e = fn*2+(l15&1), o = by*32+wc*8+(l15>>1)
  float* c_lds = (float*)lds;
  {
    int row = tid >> 1, half = tid & 1;
    *(float4*)&c_lds[row * 8 + half * 4] =
        *(const float4*)&coeff[((size_t)blockIdx.x * 256 + row) * 8 + half * 4];
  }
  __syncthreads();

  const int e0 = lane & 1;
  const int o_g = blockIdx.y * 32 + (wc << 3) + (l15 >> 1);
  if (o_g < Oeff) {
    float bb[4];
#pragma unroll
    for (int fn = 0; fn < 4; ++fn) bb[fn] = bias[(fn * 2 + e0) * bias_ld + o_g];
#pragma unroll
    for (int fm = 0; fm < 8; ++fm) {
#pragma unroll
      for (int r = 0; r < 4; ++r) {
        int n_loc = wr * 128 + fm * 16 + (lg << 2) + r;
        float s = 0.f;
#pragma unroll
        for (int fn = 0; fn < 4; ++fn)
          s += c_lds[n_loc * 8 + fn * 2 + e0] * (acc[fm][fn][r] + bb[fn]);
        s += __shfl_xor(s, 1);
        if (ELU) s = s > 0.f ? s : expm1f(s);
        if ((lane & 1) == (fm & 1))
          storev(&Y[(size_t)(blockIdx.x * 256 + n_loc) * ldY + o_g], s);
      }
    }
  }
}

// ---------------- launch ----------------
extern "C" void kernel_launch(void* const* d_in, const int* in_sizes, int n_in,
                              void* d_out, int out_size, void* d_ws, size_t ws_size,
                              hipStream_t stream)
{
  const float* latent    = (const float*)d_in[0];
  const float* condition = (const float*)d_in[1];
  const float* phase     = (const float*)d_in[2];
  const float* gw1 = (const float*)d_in[3];
  const float* gb1 = (const float*)d_in[4];
  const float* gw2 = (const float*)d_in[5];
  const float* gb2 = (const float*)d_in[6];
  const float* gw3 = (const float*)d_in[7];
  const float* gb3 = (const float*)d_in[8];
  const float* w0  = (const float*)d_in[9];
  const float* b0  = (const float*)d_in[10];
  const float* w1  = (const float*)d_in[11];
  const float* b1  = (const float*)d_in[12];
  const float* w2  = (const float*)d_in[13];
  const float* b2  = (const float*)d_in[14];

  float* out   = (float*)d_out;
  float* coeff = out + (size_t)NR * 171;

  char* ws = (char*)d_ws;
  __hip_bfloat16* x0s = (__hip_bfloat16*)ws; ws += (size_t)16 * 5 * 32768;
  __hip_bfloat16* x1s = (__hip_bfloat16*)ws; ws += (size_t)16 * 9 * 32768;
  __hip_bfloat16* x2s = (__hip_bfloat16*)ws; ws += (size_t)16 * 8 * 32768;
  __hip_bfloat16* w0s = (__hip_bfloat16*)ws; ws += (size_t)16 * 5 * 32768;
  __hip_bfloat16* w1s = (__hip_bfloat16*)ws; ws += (size_t)16 * 9 * 32768;
  __hip_bfloat16* w2s = (__hip_bfloat16*)ws; ws += (size_t)6 * 8 * 32768;
  __hip_bfloat16* y0  = (__hip_bfloat16*)ws; ws += (size_t)NR * 512 * 2;
  __hip_bfloat16* y1  = (__hip_bfloat16*)ws; ws += (size_t)NR * 512 * 2;

  // prep (B staged expert-interleaved; A staged; gate exact)
  stage_w<<<dim3(5, 64), 256, 0, stream>>>(w0, w0s, 283, 5, 512, 512);
  stage_w<<<dim3(9, 64), 256, 0, stream>>>(w1, w1s, 576, 9, 512, 512);
  stage_w<<<dim3(8, 24), 256, 0, stream>>>(w2, w2s, 512, 8, 171, 192);
  stage_x0<<<640, 256, 0, stream>>>(condition, latent, x0s);
  gate_kernel<<<256, 128, 0, stream>>>(phase, latent, gw1, gb1, gw2, gb2, gw3, gb3, coeff);

  // layer 0: fused GEMM+blend -> y0 [4096,512] bf16
  gemm8<5, true, __hip_bfloat16><<<dim3(16, 16), 512, 0, stream>>>(
      x0s, w0s, coeff, b0, y0, 512, 512, 512);
  restage_y1<<<1152, 256, 0, stream>>>(y0, latent, x1s);

  // layer 1: fused GEMM+blend -> y1 [4096,512] bf16
  gemm8<9, true, __hip_bfloat16><<<dim3(16, 16), 512, 0, stream>>>(
      x1s, w1s, coeff, b1, y1, 512, 512, 512);
  restage_y2<<<1024, 256, 0, stream>>>(y1, x2s);

  // layer 2: fused GEMM+blend -> out fp32 [4096,171]
  gemm8<8, false, float><<<dim3(16, 6), 512, 0, stream>>>(
      x2s, w2s, coeff, b2, out, 171, 171, 171);
}